// Round 1
// baseline (185.433 us; speedup 1.0000x reference)
//
#include <hip/hip_runtime.h>
#include <math.h>

#define N_OBJ 1024
#define C_DET 8
#define C_SEG 4
#define HW    784      // 28*28
#define HW4   196      // HW / 4 (float4 units)
#define NWS   (C_DET + C_DET * C_SEG)   // 8 denom + 32 A entries

// ws layout: ws[0..7] = denom[c]; ws[8 + c*4 + s] = A[c][s]

__global__ void zero_ws_kernel(float* __restrict__ ws) {
    if (threadIdx.x < NWS) ws[threadIdx.x] = 0.f;
}

__global__ __launch_bounds__(256) void overlap_kernel(
    const float* __restrict__ det,   // [N_OBJ, C_DET, HW]
    const float* __restrict__ seg,   // [N_OBJ, C_DET, C_SEG, HW]
    float* __restrict__ ws)
{
    const int c = blockIdx.y;        // det class for this block
    float accA0 = 0.f, accA1 = 0.f, accA2 = 0.f, accA3 = 0.f, accD = 0.f;

    const int total4 = N_OBJ * HW4;  // float4 elements per det class
    for (int t4 = blockIdx.x * blockDim.x + threadIdx.x; t4 < total4;
         t4 += gridDim.x * blockDim.x) {
        const int n  = t4 / HW4;
        const int p4 = t4 - n * HW4;
        const size_t drow = (size_t)(n * C_DET + c) * HW + (size_t)p4 * 4;
        const float4 d = *reinterpret_cast<const float4*>(det + drow);
        accD += (d.x + d.y) + (d.z + d.w);

        const size_t srow = (size_t)(n * C_DET + c) * (C_SEG * HW) + (size_t)p4 * 4;
        const float4 s0 = *reinterpret_cast<const float4*>(seg + srow + 0 * HW);
        const float4 s1 = *reinterpret_cast<const float4*>(seg + srow + 1 * HW);
        const float4 s2 = *reinterpret_cast<const float4*>(seg + srow + 2 * HW);
        const float4 s3 = *reinterpret_cast<const float4*>(seg + srow + 3 * HW);
        accA0 += s0.x * d.x + s0.y * d.y + s0.z * d.z + s0.w * d.w;
        accA1 += s1.x * d.x + s1.y * d.y + s1.z * d.z + s1.w * d.w;
        accA2 += s2.x * d.x + s2.y * d.y + s2.z * d.z + s2.w * d.w;
        accA3 += s3.x * d.x + s3.y * d.y + s3.z * d.z + s3.w * d.w;
    }

    // Block-reduce 5 scalars: wave shuffle (width 64) -> LDS -> 5 atomics.
    __shared__ float sred[5][4];
    const int lane = threadIdx.x & 63;
    const int wv   = threadIdx.x >> 6;
    float vals[5] = {accD, accA0, accA1, accA2, accA3};
    #pragma unroll
    for (int k = 0; k < 5; ++k) {
        float v = vals[k];
        #pragma unroll
        for (int off = 32; off > 0; off >>= 1) v += __shfl_down(v, off, 64);
        if (lane == 0) sred[k][wv] = v;
    }
    __syncthreads();
    if (threadIdx.x < 5) {
        const float v = sred[threadIdx.x][0] + sred[threadIdx.x][1]
                      + sred[threadIdx.x][2] + sred[threadIdx.x][3];
        if (threadIdx.x == 0) atomicAdd(&ws[c], v);
        else atomicAdd(&ws[C_DET + c * C_SEG + (threadIdx.x - 1)], v);
    }
}

__global__ __launch_bounds__(256) void finalize_kernel(
    const float* __restrict__ det_class,  // [N_OBJ, C_DET]
    const int* __restrict__ edge_i,
    const int* __restrict__ edge_j,
    const int n_edges,
    const float* __restrict__ ws,
    float* __restrict__ out)
{
    __shared__ float wsh[C_DET];
    if (threadIdx.x < C_DET) wsh[threadIdx.x] = 0.f;
    __syncthreads();
    if (threadIdx.x < n_edges) {
        const int i = edge_i[threadIdx.x];
        const int j = edge_j[threadIdx.x];
        atomicAdd(&wsh[j], ws[C_DET + j * C_SEG + i] / ws[j]);
    }
    __syncthreads();

    float wl[C_DET];
    #pragma unroll
    for (int k = 0; k < C_DET; ++k) wl[k] = wsh[k];

    float acc = 0.f;
    for (int n = threadIdx.x; n < N_OBJ; n += blockDim.x) {
        float p = 0.f;
        #pragma unroll
        for (int k = 0; k < C_DET; ++k)
            p += det_class[n * C_DET + k] * wl[k];
        const float lg = fmaxf(logf(p), -100.f);   // clip(log, -100) then negate
        acc += -lg;
    }

    // block reduce acc
    __shared__ float sred[4];
    const int lane = threadIdx.x & 63;
    const int wv   = threadIdx.x >> 6;
    float v = acc;
    #pragma unroll
    for (int off = 32; off > 0; off >>= 1) v += __shfl_down(v, off, 64);
    if (lane == 0) sred[wv] = v;
    __syncthreads();
    if (threadIdx.x == 0) {
        const float total = sred[0] + sred[1] + sred[2] + sred[3];
        out[0] = total * (1.0f / N_OBJ);
    }
}

extern "C" void kernel_launch(void* const* d_in, const int* in_sizes, int n_in,
                              void* d_out, int out_size, void* d_ws, size_t ws_size,
                              hipStream_t stream) {
    const float* det_class = (const float*)d_in[0];   // [1024, 8]
    const float* det       = (const float*)d_in[1];   // [1024, 8, 28, 28]
    const float* seg       = (const float*)d_in[2];   // [1024, 8, 4, 28, 28]
    const int*   edge_i    = (const int*)d_in[3];
    const int*   edge_j    = (const int*)d_in[4];
    const int    n_edges   = in_sizes[3];
    float* out = (float*)d_out;
    float* ws  = (float*)d_ws;

    zero_ws_kernel<<<1, 64, 0, stream>>>(ws);
    overlap_kernel<<<dim3(128, C_DET), 256, 0, stream>>>(det, seg, ws);
    finalize_kernel<<<1, 256, 0, stream>>>(det_class, edge_i, edge_j, n_edges, ws, out);
}

// Round 2
// 175.461 us; speedup vs baseline: 1.0568x; 1.0568x over previous
//
#include <hip/hip_runtime.h>
#include <math.h>

#define N_OBJ 1024
#define C_DET 8
#define C_SEG 4
#define HW    784      // 28*28
#define HW4   196      // HW / 4 (float4 units)
#define NBLK  128      // blocks in x per det class

typedef float f32x4 __attribute__((ext_vector_type(4)));

// ws layout: partial[(c*NBLK + bx)*5 + k], k=0 -> denom partial, k=1..4 -> A[c][k-1] partial

__global__ __launch_bounds__(256) void overlap_kernel(
    const float* __restrict__ det,   // [N_OBJ, C_DET, HW]
    const float* __restrict__ seg,   // [N_OBJ, C_DET, C_SEG, HW]
    float* __restrict__ partial)
{
    const int c  = blockIdx.y;
    const int bx = blockIdx.x;
    float accD = 0.f, accA0 = 0.f, accA1 = 0.f, accA2 = 0.f, accA3 = 0.f;

    const int total4 = N_OBJ * HW4;          // 200704 float4 per det class
    const int step   = NBLK * 256;           // 32768

    auto body = [&](int t4) {
        const int n  = t4 / HW4;             // magic-mul div
        const int p4 = t4 - n * HW4;
        const int drow = (n * C_DET + c) * HW + p4 * 4;
        const f32x4 d = __builtin_nontemporal_load(
            reinterpret_cast<const f32x4*>(det + drow));
        const int srow = (n * C_DET + c) * (C_SEG * HW) + p4 * 4;
        const f32x4 s0 = __builtin_nontemporal_load(
            reinterpret_cast<const f32x4*>(seg + srow + 0 * HW));
        const f32x4 s1 = __builtin_nontemporal_load(
            reinterpret_cast<const f32x4*>(seg + srow + 1 * HW));
        const f32x4 s2 = __builtin_nontemporal_load(
            reinterpret_cast<const f32x4*>(seg + srow + 2 * HW));
        const f32x4 s3 = __builtin_nontemporal_load(
            reinterpret_cast<const f32x4*>(seg + srow + 3 * HW));
        accD  += (d.x + d.y) + (d.z + d.w);
        accA0 += s0.x * d.x + s0.y * d.y + s0.z * d.z + s0.w * d.w;
        accA1 += s1.x * d.x + s1.y * d.y + s1.z * d.z + s1.w * d.w;
        accA2 += s2.x * d.x + s2.y * d.y + s2.z * d.z + s2.w * d.w;
        accA3 += s3.x * d.x + s3.y * d.y + s3.z * d.z + s3.w * d.w;
    };

    int t4 = bx * 256 + threadIdx.x;
    // 2-way unroll: 10 outstanding 16B loads per thread
    for (; t4 + step < total4; t4 += 2 * step) {
        body(t4);
        body(t4 + step);
    }
    if (t4 < total4) body(t4);

    // Block-reduce 5 scalars: wave shuffle (width 64) -> LDS -> direct store.
    __shared__ float sred[5][4];
    const int lane = threadIdx.x & 63;
    const int wv   = threadIdx.x >> 6;
    float vals[5] = {accD, accA0, accA1, accA2, accA3};
    #pragma unroll
    for (int k = 0; k < 5; ++k) {
        float v = vals[k];
        #pragma unroll
        for (int off = 32; off > 0; off >>= 1) v += __shfl_down(v, off, 64);
        if (lane == 0) sred[k][wv] = v;
    }
    __syncthreads();
    if (threadIdx.x < 5) {
        const float v = sred[threadIdx.x][0] + sred[threadIdx.x][1]
                      + sred[threadIdx.x][2] + sred[threadIdx.x][3];
        partial[(c * NBLK + bx) * 5 + threadIdx.x] = v;
    }
}

__global__ __launch_bounds__(256) void finalize_kernel(
    const float* __restrict__ det_class,  // [N_OBJ, C_DET]
    const int* __restrict__ edge_i,
    const int* __restrict__ edge_j,
    const int n_edges,
    const float* __restrict__ partial,
    float* __restrict__ out)
{
    __shared__ float A[C_DET][C_SEG];
    __shared__ float D[C_DET];
    __shared__ float wsh[C_DET];
    const int tid = threadIdx.x;

    // Stage 1: reduce the 1024x5 block partials to A[8][4] and D[8].
    if (tid < 40) {
        const int c = tid / 5;
        const int k = tid - c * 5;
        float s = 0.f;
        for (int b = 0; b < NBLK; ++b)
            s += partial[(c * NBLK + b) * 5 + k];
        if (k == 0) D[c] = s;
        else        A[c][k - 1] = s;
    }
    if (tid < C_DET) wsh[tid] = 0.f;
    __syncthreads();

    // Stage 2: per-edge weights accumulated onto det class j.
    if (tid < n_edges) {
        const int i = edge_i[tid];
        const int j = edge_j[tid];
        atomicAdd(&wsh[j], A[j][i] / D[j]);
    }
    __syncthreads();

    float wl[C_DET];
    #pragma unroll
    for (int k = 0; k < C_DET; ++k) wl[k] = wsh[k];

    // Stage 3: probs = det_class @ w; BCE vs ones = mean(-clip(log p, -100)).
    float acc = 0.f;
    for (int n = tid; n < N_OBJ; n += 256) {
        const f32x4 a = *reinterpret_cast<const f32x4*>(det_class + n * C_DET);
        const f32x4 b = *reinterpret_cast<const f32x4*>(det_class + n * C_DET + 4);
        float p = a.x * wl[0] + a.y * wl[1] + a.z * wl[2] + a.w * wl[3]
                + b.x * wl[4] + b.y * wl[5] + b.z * wl[6] + b.w * wl[7];
        acc += -fmaxf(logf(p), -100.f);
    }

    __shared__ float sred[4];
    const int lane = tid & 63;
    const int wv   = tid >> 6;
    float v = acc;
    #pragma unroll
    for (int off = 32; off > 0; off >>= 1) v += __shfl_down(v, off, 64);
    if (lane == 0) sred[wv] = v;
    __syncthreads();
    if (tid == 0) {
        out[0] = (sred[0] + sred[1] + sred[2] + sred[3]) * (1.0f / N_OBJ);
    }
}

extern "C" void kernel_launch(void* const* d_in, const int* in_sizes, int n_in,
                              void* d_out, int out_size, void* d_ws, size_t ws_size,
                              hipStream_t stream) {
    const float* det_class = (const float*)d_in[0];   // [1024, 8]
    const float* det       = (const float*)d_in[1];   // [1024, 8, 28, 28]
    const float* seg       = (const float*)d_in[2];   // [1024, 8, 4, 28, 28]
    const int*   edge_i    = (const int*)d_in[3];
    const int*   edge_j    = (const int*)d_in[4];
    const int    n_edges   = in_sizes[3];
    float* out = (float*)d_out;
    float* partial = (float*)d_ws;   // 8*128*5 floats = 20 KB

    overlap_kernel<<<dim3(NBLK, C_DET), 256, 0, stream>>>(det, seg, partial);
    finalize_kernel<<<1, 256, 0, stream>>>(det_class, edge_i, edge_j, n_edges,
                                           partial, out);
}